// Round 5
// baseline (145.789 us; speedup 1.0000x reference)
//
#include <hip/hip_runtime.h>
#include <hip/hip_bf16.h>

// CompletePatchReadout: grouped GEMM (128 patches, M=32 K=1536 N=768) + bias + scatter.
// Round-5 structure: ZERO LDS, ZERO barriers. Every thread streams its own W columns
// (dword gather, fragment layout) and x rows (dwordx4, L3-resident) fully independently;
// fp32->bf16 via hardware cvt casts (round-2/4 used a 5-op manual RNE — convoy on the
// dependent path). XCD-swizzled block ids. W = 604 MB read-once; floor ~96-100 us.

constexpr int T      = 12;
constexpr int P      = 128;
constexpr int F      = 128;
constexpr int K      = T * F;        // 1536
constexpr int N      = 768;
constexpr int NPP    = 64;
constexpr int H      = 12;
constexpr int NNODES = P * NPP;      // 8192
constexpr int BN     = 128;
constexpr int NT     = N / BN;       // 6
constexpr int TPF    = T * P * F;
constexpr int PF     = P * F;
constexpr int NHS    = K / 32;       // 48 half-steps (one 16x16x32 MFMA K-slab each)

typedef __attribute__((ext_vector_type(8))) short  bf16x8;
typedef __attribute__((ext_vector_type(4))) float  f32x4;

union BF8 { unsigned short s[8]; bf16x8 v; };

__device__ inline unsigned short f2bfu(float f) {   // hw RNE cvt (v_cvt_pk-fusable)
    return __bfloat16_as_ushort(__float2bfloat16(f));
}

__global__ __launch_bounds__(256, 3)
void patch_readout_kernel(const float* __restrict__ x,
                          const float* __restrict__ W,
                          const float* __restrict__ bias,
                          const int*   __restrict__ map,
                          float*       __restrict__ out)
{
    // Bijective XCD swizzle (768 = 8 XCDs * 96): each XCD gets 16 whole patches,
    // so the 6 blocks sharing a patch's x-slice hit the same per-XCD L2.
    const int bid = blockIdx.y * NT + blockIdx.x;     // launch id 0..767
    const int lgc = (bid & 7) * 96 + (bid >> 3);      // logical work id
    const int p   = lgc / NT;
    const int n0  = (lgc % NT) * BN;

    const int tid  = threadIdx.x;
    const int lane = tid & 63;
    const int wv   = tid >> 6;        // wave -> 32-col slice of BN
    const int r    = lane & 15;
    const int c    = lane >> 4;       // k-octet within 32-k slab

    // B (W) fragment base: lane (r,c), wave wv: col = n0+wv*32+ni*16+r, k = hs*32+8c+j
    const float* wb  = W + (size_t)p * K * N + (size_t)(8 * c) * N + (n0 + wv * 32 + r);
    // A (x) fragment bases per mi: m = mi*16 + r, k-octet 8c contiguous within a t-chunk
    const float* xb0 = x + (size_t)r * TPF        + p * F + 8 * c;
    const float* xb1 = x + (size_t)(16 + r) * TPF + p * F + 8 * c;

    f32x4 acc[2][2] = {};             // [mi][ni]

    #pragma unroll 2
    for (int hs = 0; hs < NHS; ++hs) {
        // x: k = hs*32 + 8c + (0..7) -> t = hs>>2, f = (hs&3)*32 + 8c (never crosses t)
        const int xoff = (hs >> 2) * PF + (hs & 3) * 32;
        const f32x4 xa0 = *(const f32x4*)(xb0 + xoff);
        const f32x4 xa1 = *(const f32x4*)(xb0 + xoff + 4);
        const f32x4 xa2 = *(const f32x4*)(xb1 + xoff);
        const f32x4 xa3 = *(const f32x4*)(xb1 + xoff + 4);

        // W: 16 dword gathers (stride N between j's), 64B segments across r-lanes
        const float* wr = wb + (size_t)hs * 32 * N;
        float wf0[8], wf1[8];         // [j] for ni=0,1
        #pragma unroll
        for (int j = 0; j < 8; ++j) {
            wf0[j] = wr[j * N];
            wf1[j] = wr[j * N + 16];
        }

        // convert to bf16 fragments (hw cvt)
        BF8 ax0, ax1, bx0, bx1;
        ax0.s[0] = f2bfu(xa0.x); ax0.s[1] = f2bfu(xa0.y);
        ax0.s[2] = f2bfu(xa0.z); ax0.s[3] = f2bfu(xa0.w);
        ax0.s[4] = f2bfu(xa1.x); ax0.s[5] = f2bfu(xa1.y);
        ax0.s[6] = f2bfu(xa1.z); ax0.s[7] = f2bfu(xa1.w);
        ax1.s[0] = f2bfu(xa2.x); ax1.s[1] = f2bfu(xa2.y);
        ax1.s[2] = f2bfu(xa2.z); ax1.s[3] = f2bfu(xa2.w);
        ax1.s[4] = f2bfu(xa3.x); ax1.s[5] = f2bfu(xa3.y);
        ax1.s[6] = f2bfu(xa3.z); ax1.s[7] = f2bfu(xa3.w);
        #pragma unroll
        for (int j = 0; j < 8; ++j) {
            bx0.s[j] = f2bfu(wf0[j]);
            bx1.s[j] = f2bfu(wf1[j]);
        }

        acc[0][0] = __builtin_amdgcn_mfma_f32_16x16x32_bf16(ax0.v, bx0.v, acc[0][0], 0, 0, 0);
        acc[0][1] = __builtin_amdgcn_mfma_f32_16x16x32_bf16(ax0.v, bx1.v, acc[0][1], 0, 0, 0);
        acc[1][0] = __builtin_amdgcn_mfma_f32_16x16x32_bf16(ax1.v, bx0.v, acc[1][0], 0, 0, 0);
        acc[1][1] = __builtin_amdgcn_mfma_f32_16x16x32_bf16(ax1.v, bx1.v, acc[1][1], 0, 0, 0);
    }

    // ---- epilogue: bias + permutation scatter (layout verified rounds 2/4) ----
    #pragma unroll
    for (int ni = 0; ni < 2; ++ni) {
        const int col = n0 + wv * 32 + ni * 16 + r;   // output col in [0,768)
        const int nl  = col / H;                      // patch-local node
        const int h   = col - nl * H;                 // horizon
        const int g   = map[p * NPP + nl];            // global node
        const float bv = bias[p * N + col];
        #pragma unroll
        for (int mi = 0; mi < 2; ++mi) {
            #pragma unroll
            for (int i = 0; i < 4; ++i) {
                const int b = mi * 16 + c * 4 + i;    // batch row
                out[((size_t)b * NNODES + g) * H + h] = acc[mi][ni][i] + bv;
            }
        }
    }
}

extern "C" void kernel_launch(void* const* d_in, const int* in_sizes, int n_in,
                              void* d_out, int out_size, void* d_ws, size_t ws_size,
                              hipStream_t stream) {
    const float* x    = (const float*)d_in[0];
    const float* W    = (const float*)d_in[1];
    const float* bias = (const float*)d_in[2];
    const int*   map  = (const int*)d_in[3];
    float*       out  = (float*)d_out;

    dim3 grid(NT, P);   // 768 blocks = 3/CU exactly
    dim3 block(256);
    patch_readout_kernel<<<grid, block, 0, stream>>>(x, W, bias, map, out);
}

// Round 6
// 135.219 us; speedup vs baseline: 1.0782x; 1.0782x over previous
//
#include <hip/hip_runtime.h>
#include <hip/hip_bf16.h>

// CompletePatchReadout: grouped GEMM (128 patches, M=32 K=1536 N=768) + bias + scatter.
// Round-6: ALL global loads are dense wave-coalesced dwordx4 (G13: scalar dword gathers
// capped R2/R4/R5 at ~4.7-5 TB/s). W tile loaded row-dense to regs, bf16-packed, written
// TRANSPOSED to LDS in B-fragment layout; x staged per-tile (R2-verified addressing).
// One barrier per K64-step; prefetch is never drained by a barrier.

constexpr int T      = 12;
constexpr int P      = 128;
constexpr int F      = 128;
constexpr int K      = T * F;       // 1536
constexpr int N      = 768;
constexpr int NPP    = 64;
constexpr int H      = 12;
constexpr int NNODES = P * NPP;     // 8192
constexpr int BN     = 128;
constexpr int NT     = N / BN;      // 6
constexpr int NSTEP  = K / 64;      // 24 K-steps
constexpr int TPF    = T * P * F;
constexpr int PF     = P * F;

typedef __attribute__((ext_vector_type(8))) short        bf16x8;
typedef __attribute__((ext_vector_type(4))) float        f32x4;
typedef __attribute__((ext_vector_type(4))) unsigned int u32x4;

__device__ inline unsigned short f2bfu(float f) {   // hw RNE cvt
    return __bfloat16_as_ushort(__float2bfloat16(f));
}
__device__ inline unsigned int pk2(float lo, float hi) {
    return (unsigned int)f2bfu(lo) | ((unsigned int)f2bfu(hi) << 16);
}

__global__ __launch_bounds__(256, 3)
void patch_readout_kernel(const float* __restrict__ x,
                          const float* __restrict__ W,
                          const float* __restrict__ bias,
                          const int*   __restrict__ map,
                          float*       __restrict__ out)
{
    // W tile: [col 0..127][koct 0..7][8 bf16] = 16 KB per buffer (k-major per col!).
    // x tile: [row 0..31][64 k bf16]          =  4 KB per buffer.
    __shared__ short Wl[2][128 * 64];
    __shared__ short Xl[2][32 * 64];
    char* wl = (char*)&Wl[0][0];
    char* xl = (char*)&Xl[0][0];

    // XCD swizzle: 768 = 8*96; same-patch blocks land on one XCD (x L2 reuse).
    const int bid = blockIdx.y * NT + blockIdx.x;
    const int lgc = (bid & 7) * 96 + (bid >> 3);
    const int p   = lgc / NT;
    const int n0  = (lgc % NT) * BN;

    const int tid  = threadIdx.x;
    const int lane = tid & 63;
    const int wv   = tid >> 6;       // wave -> 32-col slice
    const int r    = lane & 15;
    const int c    = lane >> 4;

    // --- global W loads: thread (koct, q) owns rows 8*koct..+7, cols 4q..4q+3 (dense) ---
    const int koct = tid >> 5;       // 0..7
    const int q    = tid & 31;       // col-quad
    const float* wg = W + (size_t)p * K * N + (size_t)(8 * koct) * N + (n0 + 4 * q);

    // --- x staging: thread (xrow, xsub) -> row xrow, k-octet xsub (R2-verified) ---
    const int xrow = tid >> 3;
    const int xsub = tid & 7;
    const float* xg  = x + (size_t)xrow * TPF + p * F + xsub * 8;
    const int    xwb = xrow * 128 + ((xsub * 16) ^ ((xrow & 7) << 4));

    f32x4 acc[2][2] = {};
    f32x4 ws[8];                     // staged W: [j] rows, 4 cols each
    f32x4 xs[2];                     // staged x

    auto issue = [&](int kt) {       // dense dwordx4 only
        const size_t kofs = (size_t)kt * 64 * N;
        #pragma unroll
        for (int j = 0; j < 8; ++j)
            ws[j] = *(const f32x4*)(wg + kofs + (size_t)j * N);
        const int xo = (kt >> 1) * PF + (kt & 1) * 64;
        xs[0] = *(const f32x4*)(xg + xo);
        xs[1] = *(const f32x4*)(xg + xo + 4);
    };

    auto writeLds = [&](int d) {     // pack bf16 + transposed LDS store
        #pragma unroll
        for (int i = 0; i < 4; ++i) {
            u32x4 wd;
            wd.x = pk2(ws[0][i], ws[1][i]);
            wd.y = pk2(ws[2][i], ws[3][i]);
            wd.z = pk2(ws[4][i], ws[5][i]);
            wd.w = pk2(ws[6][i], ws[7][i]);
            const int col = 4 * q + i;
            *(u32x4*)(wl + d * 16384 + col * 128 + ((koct * 16) ^ ((col & 7) << 4))) = wd;
        }
        bf16x8 xv;
        #pragma unroll
        for (int e = 0; e < 4; ++e) {
            xv[e]     = (short)f2bfu(xs[0][e]);
            xv[4 + e] = (short)f2bfu(xs[1][e]);
        }
        *(bf16x8*)(xl + d * 4096 + xwb) = xv;
    };

    auto compute = [&](int d) {
        #pragma unroll
        for (int kc = 0; kc < 2; ++kc) {
            bf16x8 af[2], bfr[2];
            #pragma unroll
            for (int mi = 0; mi < 2; ++mi) {
                const int row = mi * 16 + r;
                af[mi] = *(const bf16x8*)(xl + d * 4096 + row * 128 +
                                          ((kc * 64 + c * 16) ^ ((row & 7) << 4)));
            }
            #pragma unroll
            for (int ni = 0; ni < 2; ++ni) {
                const int col = wv * 32 + ni * 16 + r;  // B frag: k=kc*32+8c+j, this col
                bfr[ni] = *(const bf16x8*)(wl + d * 16384 + col * 128 +
                                           ((kc * 64 + c * 16) ^ ((col & 7) << 4)));
            }
            #pragma unroll
            for (int mi = 0; mi < 2; ++mi)
                #pragma unroll
                for (int ni = 0; ni < 2; ++ni)
                    acc[mi][ni] = __builtin_amdgcn_mfma_f32_16x16x32_bf16(
                        af[mi], bfr[ni], acc[mi][ni], 0, 0, 0);
        }
    };

    // prologue: tile 0 -> LDS, start tile 1 in flight
    issue(0);
    writeLds(0);
    __syncthreads();
    issue(1);

    for (int kt = 0; kt < NSTEP; ++kt) {
        const int d = kt & 1;
        compute(d);                  // tile kt; loads(kt+1) flying underneath
        if (kt < NSTEP - 1) {
            writeLds(d ^ 1);         // counted vmcnt waits inside; WAR safe (prev barrier)
            __syncthreads();         // nothing in flight -> drain-free barrier
            if (kt < NSTEP - 2) issue(kt + 2);  // flies across next compute
        }
    }

    // ---- epilogue: bias + permutation scatter (verified rounds 2/4/5) ----
    #pragma unroll
    for (int ni = 0; ni < 2; ++ni) {
        const int col = n0 + wv * 32 + ni * 16 + r;
        const int nl  = col / H;
        const int h   = col - nl * H;
        const int g   = map[p * NPP + nl];
        const float bv = bias[p * N + col];
        #pragma unroll
        for (int mi = 0; mi < 2; ++mi) {
            #pragma unroll
            for (int i = 0; i < 4; ++i) {
                const int b = mi * 16 + c * 4 + i;
                out[((size_t)b * NNODES + g) * H + h] = acc[mi][ni][i] + bv;
            }
        }
    }
}

extern "C" void kernel_launch(void* const* d_in, const int* in_sizes, int n_in,
                              void* d_out, int out_size, void* d_ws, size_t ws_size,
                              hipStream_t stream) {
    const float* x    = (const float*)d_in[0];
    const float* W    = (const float*)d_in[1];
    const float* bias = (const float*)d_in[2];
    const int*   map  = (const int*)d_in[3];
    float*       out  = (float*)d_out;

    dim3 grid(NT, P);   // 768 blocks
    dim3 block(256);
    patch_readout_kernel<<<grid, block, 0, stream>>>(x, W, bias, map, out);
}

// Round 8
// 125.237 us; speedup vs baseline: 1.1641x; 1.0797x over previous
//
#include <hip/hip_runtime.h>
#include <hip/hip_bf16.h>

// CompletePatchReadout: grouped GEMM (128 patches, M=32 K=1536 N=768) + bias + scatter.
// Round-7 resubmit (round-7 bench died on UnresponsiveContainer before running).
// BN=384, 256 blocks = 1/CU. Attacks the two never-varied invariants:
//  (a) W DRAM pattern: 1536B row segments (vs 512B/3KB strided), 2 streams/patch (vs 6)
//  (b) x duplication: whole x-panel staged ONCE in LDS (96KB bf16) -> x read 1-2x total
// W: K32 tiles, reg-prefetch 1 step ahead, bf16-pack, transposed LDS store with
// (col ^ col>>3)&7 slot swizzle (conflict-minimal BOTH sides; R6's writes were 32-way).
// One barrier/step; drains benign (step ~1.8us >> HBM latency).

constexpr int T      = 12;
constexpr int P      = 128;
constexpr int F      = 128;
constexpr int K      = T * F;        // 1536
constexpr int N      = 768;
constexpr int NPP    = 64;
constexpr int H      = 12;
constexpr int NNODES = P * NPP;      // 8192
constexpr int BN     = 384;          // N-half per block
constexpr int NSTEP  = 48;           // K32 steps
constexpr int TPF    = T * P * F;
constexpr int PF     = P * F;

typedef __attribute__((ext_vector_type(8))) short        bf16x8;
typedef __attribute__((ext_vector_type(4))) float        f32x4;
typedef __attribute__((ext_vector_type(4))) unsigned int u32x4;

__device__ inline unsigned short f2bfu(float f) {
    return __bfloat16_as_ushort(__float2bfloat16(f));
}
__device__ inline unsigned int pk2(float lo, float hi) {
    return (unsigned int)f2bfu(lo) | ((unsigned int)f2bfu(hi) << 16);
}

__global__ __launch_bounds__(384, 1)
void patch_readout_kernel(const float* __restrict__ x,
                          const float* __restrict__ W,
                          const float* __restrict__ bias,
                          const int*   __restrict__ map,
                          float*       __restrict__ out)
{
    __shared__ short Xs[32 * K];          // 96 KB: whole x-panel, bf16, swizzled
    __shared__ short Ws2[2][4 * BN * 8];  // 2 x 24 KB: W K32-tile, [octet][col][8 bf16]
    char* xl  = (char*)&Xs[0];
    char* wlb = (char*)&Ws2[0][0];

    // XCD swizzle: 256 blocks = 8 XCDs x 32; patch-pair (2 blocks) lands on one XCD.
    const int bid = blockIdx.x;
    const int lgc = (bid & 7) * 32 + (bid >> 3);
    const int p   = lgc >> 1;
    const int n0  = (lgc & 1) * BN;

    const int tid  = threadIdx.x;         // 0..383 (6 waves)
    const int lane = tid & 63;
    const int wv   = tid >> 6;            // wave -> 64-col slice
    const int r    = lane & 15;
    const int c    = lane >> 4;           // k-octet 0..3 within K32

    // --- W loaders: thread (c2,q) owns k-octet c2, cols 4q..4q+3 (dense dwordx4) ---
    const int c2 = tid / 96;              // 0..3
    const int q  = tid - c2 * 96;         // 0..95
    const float* wg = W + (size_t)p * K * N + (size_t)(8 * c2) * N + (n0 + 4 * q);

    f32x4 ws[8];                          // prefetch set: 8 rows x 4 cols fp32

    auto issueW = [&](int s) {
        #pragma unroll
        for (int j = 0; j < 8; ++j)
            ws[j] = *(const f32x4*)(wg + (size_t)(s * 32 + j) * N);
    };

    auto writeW = [&](int d) {            // pack + transposed store, swizzled slots
        char* wl = wlb + d * 24576 + c2 * 6144;
        #pragma unroll
        for (int i = 0; i < 4; ++i) {
            u32x4 wd;
            wd.x = pk2(ws[0][i], ws[1][i]);
            wd.y = pk2(ws[2][i], ws[3][i]);
            wd.z = pk2(ws[4][i], ws[5][i]);
            wd.w = pk2(ws[6][i], ws[7][i]);
            const int col = 4 * q + i;
            *(u32x4*)(wl + ((col * 16) ^ (((col >> 3) & 7) << 4))) = wd;
        }
    };

    auto stageX = [&]() {                 // whole panel, once: 32 rows x 1536 k
        const int row = tid / 12;         // 384 = 32 x 12 exact
        const int sub = tid - row * 12;   // t-chunk
        const float* xg = x + (size_t)row * TPF + (size_t)sub * PF + (size_t)p * F;
        char* xw = xl + row * 3072;
        const int sw = (row & 7) << 4;
        #pragma unroll
        for (int ci = 0; ci < 16; ++ci) {
            f32x4 v0 = *(const f32x4*)(xg + ci * 8);
            f32x4 v1 = *(const f32x4*)(xg + ci * 8 + 4);
            bf16x8 xv;
            xv[0] = (short)f2bfu(v0.x); xv[1] = (short)f2bfu(v0.y);
            xv[2] = (short)f2bfu(v0.z); xv[3] = (short)f2bfu(v0.w);
            xv[4] = (short)f2bfu(v1.x); xv[5] = (short)f2bfu(v1.y);
            xv[6] = (short)f2bfu(v1.z); xv[7] = (short)f2bfu(v1.w);
            *(bf16x8*)(xw + ((sub * 256 + ci * 16) ^ sw)) = xv;
        }
    };

    f32x4 acc[2][4] = {};                 // [mi][ni]

    auto compute = [&](int s, int d) {
        const char* wl = wlb + d * 24576 + c * 6144;
        bf16x8 af[2];
        #pragma unroll
        for (int mi = 0; mi < 2; ++mi) {
            const int row = mi * 16 + r;
            af[mi] = *(const bf16x8*)(xl + row * 3072 +
                                      ((s * 64 + c * 16) ^ ((row & 7) << 4)));
        }
        #pragma unroll
        for (int ni = 0; ni < 4; ++ni) {
            const int col = wv * 64 + ni * 16 + r;
            bf16x8 bf = *(const bf16x8*)(wl + ((col * 16) ^ (((col >> 3) & 7) << 4)));
            #pragma unroll
            for (int mi = 0; mi < 2; ++mi)
                acc[mi][ni] = __builtin_amdgcn_mfma_f32_16x16x32_bf16(
                    af[mi], bf, acc[mi][ni], 0, 0, 0);
        }
    };

    // prologue: W tile 0 flies while x stages
    issueW(0);
    stageX();
    writeW(0);

    for (int s = 0; s < NSTEP; ++s) {
        __syncthreads();                  // buf (s&1) + x visible
        if (s < NSTEP - 1) issueW(s + 1);
        compute(s, s & 1);
        if (s < NSTEP - 1) writeW((s + 1) & 1);  // WAR vs compute(s-1): this step's bar
    }

    // ---- epilogue: bias + permutation scatter (verified layout) ----
    #pragma unroll
    for (int ni = 0; ni < 4; ++ni) {
        const int col = n0 + wv * 64 + ni * 16 + r;
        const int nl  = col / H;
        const int h   = col - nl * H;
        const int g   = map[p * NPP + nl];
        const float bv = bias[p * N + col];
        #pragma unroll
        for (int mi = 0; mi < 2; ++mi) {
            #pragma unroll
            for (int i = 0; i < 4; ++i) {
                const int b = mi * 16 + c * 4 + i;
                out[((size_t)b * NNODES + g) * H + h] = acc[mi][ni][i] + bv;
            }
        }
    }
}

extern "C" void kernel_launch(void* const* d_in, const int* in_sizes, int n_in,
                              void* d_out, int out_size, void* d_ws, size_t ws_size,
                              hipStream_t stream) {
    const float* x    = (const float*)d_in[0];
    const float* W    = (const float*)d_in[1];
    const float* bias = (const float*)d_in[2];
    const int*   map  = (const int*)d_in[3];
    float*       out  = (float*)d_out;

    dim3 grid(256);     // 1 block per CU exactly
    dim3 block(384);
    patch_readout_kernel<<<grid, block, 0, stream>>>(x, W, bias, map, out);
}